// Round 5
// baseline (488.699 us; speedup 1.0000x reference)
//
#include <hip/hip_runtime.h>
#include <math.h>

#define NH      16
#define D_NOPE  128
#define D_ROPE  64
#define D_QK    192
#define D_V     128
#define KV_LORA 512
#define NB      2
#define SEQ     2048
#define NTOK    (NB*SEQ)          // 4096
#define QROW    (NH*D_QK)         // 3072
#define KVBROW  (NH*(D_NOPE+D_V)) // 4096
#define EPSF    1e-6f

typedef unsigned short u16;
typedef float  floatx4 __attribute__((ext_vector_type(4)));
typedef __bf16 bf16x8  __attribute__((ext_vector_type(8)));
typedef u16    u16x4   __attribute__((ext_vector_type(4)));
typedef u16    u16x8   __attribute__((ext_vector_type(8)));

__device__ __forceinline__ u16 f2bf(float f) {
    unsigned u = __builtin_bit_cast(unsigned, f);
    return (u16)((u + 0x7fffu + ((u >> 16) & 1u)) >> 16);
}

__device__ __forceinline__ void async_copy16(const void* g, void* l) {
    __builtin_amdgcn_global_load_lds(
        (const __attribute__((address_space(1))) unsigned int*)g,
        (__attribute__((address_space(3))) unsigned int*)l,
        16, 0, 0);
}

// ---------------------------------------------------------------------------
// Fused fp32->bf16 cast of all 5 weight/activation arrays in ONE dispatch.
// ---------------------------------------------------------------------------
__global__ __launch_bounds__(256) void cast_all(const float* __restrict__ x,
                                                const float* __restrict__ wq,
                                                const float* __restrict__ wkva,
                                                const float* __restrict__ wkvb,
                                                const float* __restrict__ wo,
                                                u16* __restrict__ xb,
                                                u16* __restrict__ wqb,
                                                u16* __restrict__ wkvab,
                                                u16* __restrict__ wkvbb,
                                                u16* __restrict__ wob) {
    int blk = blockIdx.x;
    const float* src; u16* dst; bool pad = false;
    if (blk < 8192)        { src = x;    dst = xb; }
    else if (blk < 14336)  { blk -= 8192;  src = wq;   dst = wqb; }
    else if (blk < 15616)  { blk -= 14336; src = wkva; dst = wkvab; pad = true; }
    else if (blk < 17664)  { blk -= 15616; src = wkvb; dst = wkvbb; }
    else                   { blk -= 17664; src = wo;   dst = wob; }
    const int i = (blk * 256 + threadIdx.x) * 4;
    u16x4 o;
    if (pad && (i >> 11) >= 576) {
        o[0] = 0; o[1] = 0; o[2] = 0; o[3] = 0;
    } else {
        const float4 v = *(const float4*)&src[i];
        o[0] = f2bf(v.x); o[1] = f2bf(v.y); o[2] = f2bf(v.z); o[3] = f2bf(v.w);
    }
    *(u16x4*)&dst[i] = o;
}

// ---------------------------------------------------------------------------
// bf16 NT MFMA GEMM (m97 recipe), templated epilogue:
//   MODE 0: fp32 C[M,N] | MODE 1: bf16 C[M,N] | MODE 2: kv-split kbuf/vT.
// ---------------------------------------------------------------------------
template<int MODE>
__global__ __launch_bounds__(256) void gemm_mfma(const u16* __restrict__ A,
                                                 const u16* __restrict__ B,
                                                 void* __restrict__ Cout,
                                                 u16* __restrict__ kbuf,
                                                 u16* __restrict__ vT,
                                                 int M, int N, int K) {
    __shared__ u16 As[128 * 32];
    __shared__ u16 Bs[128 * 32];
    const int tid  = threadIdx.x;
    const int wave = tid >> 6, lane = tid & 63;
    const int m0 = blockIdx.y * 128, n0 = blockIdx.x * 128;
    const int wm = (wave & 1) * 64, wn = (wave >> 1) * 64;

    const int srow = wave * 32 + (lane >> 2);
    const int kch  = (lane & 3) * 8;
    const u16* gA0 = A + (size_t)(m0 + srow) * K + kch;
    const u16* gA1 = gA0 + (size_t)16 * K;
    const u16* gB0 = B + (size_t)(n0 + srow) * K + kch;
    const u16* gB1 = gB0 + (size_t)16 * K;
    u16* lA0 = &As[(wave * 32) * 32];
    u16* lA1 = &As[(wave * 32 + 16) * 32];
    u16* lB0 = &Bs[(wave * 32) * 32];
    u16* lB1 = &Bs[(wave * 32 + 16) * 32];

    floatx4 acc[4][4];
#pragma unroll
    for (int i = 0; i < 4; ++i)
#pragma unroll
        for (int j = 0; j < 4; ++j) acc[i][j] = 0.f;

    const int lrow = lane & 15;
    const int lkh  = (lane >> 4) * 8;

    for (int k0 = 0; k0 < K; k0 += 32) {
        __syncthreads();
        async_copy16(gA0 + k0, lA0);
        async_copy16(gA1 + k0, lA1);
        async_copy16(gB0 + k0, lB0);
        async_copy16(gB1 + k0, lB1);
        __syncthreads();
        bf16x8 a[4], b[4];
#pragma unroll
        for (int mi = 0; mi < 4; ++mi)
            a[mi] = *(const bf16x8*)&As[(wm + mi * 16 + lrow) * 32 + lkh];
#pragma unroll
        for (int ni = 0; ni < 4; ++ni)
            b[ni] = *(const bf16x8*)&Bs[(wn + ni * 16 + lrow) * 32 + lkh];
#pragma unroll
        for (int mi = 0; mi < 4; ++mi)
#pragma unroll
            for (int ni = 0; ni < 4; ++ni)
                acc[mi][ni] = __builtin_amdgcn_mfma_f32_16x16x32_bf16(
                    a[mi], b[ni], acc[mi][ni], 0, 0, 0);
    }

    const int crow = (lane >> 4) * 4, ccol = lane & 15;
#pragma unroll
    for (int mi = 0; mi < 4; ++mi)
#pragma unroll
        for (int ni = 0; ni < 4; ++ni) {
            const int m = m0 + wm + mi * 16 + crow;
            const int c = n0 + wn + ni * 16 + ccol;
            if (MODE == 0) {
                float* cp = (float*)Cout + (size_t)m * N + c;
#pragma unroll
                for (int r = 0; r < 4; ++r) cp[(size_t)r * N] = acc[mi][ni][r];
            } else if (MODE == 1) {
                u16* cp = (u16*)Cout + (size_t)m * N + c;
#pragma unroll
                for (int r = 0; r < 4; ++r) cp[(size_t)r * N] = f2bf(acc[mi][ni][r]);
            } else {
                const int hh = c >> 8, j = c & 255;
                const int bb = m >> 11, t = m & 2047;
                if (j < 128) {
#pragma unroll
                    for (int r = 0; r < 4; ++r)
                        kbuf[(((size_t)hh * 2 + bb) * 2048 + t + r) * 192 + j] =
                            f2bf(acc[mi][ni][r]);
                } else {
                    u16x4 pk;
#pragma unroll
                    for (int r = 0; r < 4; ++r) pk[r] = f2bf(acc[mi][ni][r]);
                    *(u16x4*)&vT[(((size_t)hh * 2 + bb) * 128 + (j - 128)) * 2048 + t] = pk;
                }
            }
        }
}

// NOTE: the reference computes q_pe = rotary(q_pe) but then uses the ORIGINAL
// (unrotated) q in the score einsum — the rotated q_pe is dead code there.
// So q gets NO RoPE; only k_pe is rotated.

// ---------------------------------------------------------------------------
// Per-token: rmsnorm(kv_c)*w -> kvn_bf; rotary(k_pe) -> kbuf[h][b][t][128..191].
// ---------------------------------------------------------------------------
__global__ __launch_bounds__(256) void kv_fix(const float* __restrict__ kv_raw,
                                              const float* __restrict__ w,
                                              const float* __restrict__ fcos,
                                              const float* __restrict__ fsin,
                                              u16* __restrict__ kvn_bf,
                                              u16* __restrict__ kbuf) {
    const int row = blockIdx.x;
    const int tid = threadIdx.x;
    const float* src = kv_raw + (size_t)row * 640;
    const float v0 = src[tid];
    const float v1 = src[256 + tid];
    float ss = v0 * v0 + v1 * v1;
#pragma unroll
    for (int off = 32; off > 0; off >>= 1) ss += __shfl_down(ss, off, 64);
    __shared__ float red[4];
    __shared__ float kpe_s[64];
    if ((tid & 63) == 0) red[tid >> 6] = ss;
    if (tid < 32) {
        const int s = row & (SEQ - 1);
        const float c  = fcos[s * 32 + tid];
        const float sn = fsin[s * 32 + tid];
        const float xr = src[KV_LORA + 2 * tid];
        const float xi = src[KV_LORA + 2 * tid + 1];
        kpe_s[2 * tid]     = xr * c - xi * sn;
        kpe_s[2 * tid + 1] = xr * sn + xi * c;
    }
    __syncthreads();
    const float tot = red[0] + red[1] + red[2] + red[3];
    const float inv = rsqrtf(tot * (1.0f / KV_LORA) + EPSF);
    kvn_bf[(size_t)row * KV_LORA + tid]       = f2bf(v0 * inv * w[tid]);
    kvn_bf[(size_t)row * KV_LORA + 256 + tid] = f2bf(v1 * inv * w[256 + tid]);
    const int bb = row >> 11, t = row & 2047;
    const int hh = tid >> 4, dg = (tid & 15) * 4;
    u16x4 pk;
#pragma unroll
    for (int j = 0; j < 4; ++j) pk[j] = f2bf(kpe_s[dg + j]);
    *(u16x4*)&kbuf[(((size_t)hh * 2 + bb) * 2048 + t) * 192 + 128 + dg] = pk;
}

// ---------------------------------------------------------------------------
// MFMA flash attention v8: load-balanced chunk interleaving.
//   Root cause of the 17%-MfmaUtil plateau (v4-v7): contiguous 128-row
//   q-tiles -> per-CU block pair (qt,15-qt) collapses to 1 block/CU after
//   2qt+2 iters (measured Occupancy 13.2% == predicted 13.3%), leaving the
//   serial per-tile chain fully exposed at 1 wave/SIMD.
//   Fix: per (h,b), 128 chunks of 16 q-rows. Block j in [0,16) owns chunks
//   {j+16i}; wave w: g0 -> chunk j+16w, g1 -> chunk j+16(7-w).
//   Per-wave active tiles = 30+2*(j>>2) (equal for ALL waves/blocks);
//   block iters = 29..32. All CUs stay at 2 blocks x 4 waves to the end.
//   Wave-uniform act0/act1 guards skip QK/softmax/PV for retired chunks.
//   Staging address math hoisted out of the k-loop (src/dst pointer arrays).
//   Keeps v7: T2 both-sides XOR swizzle, counted vmcnt, setprio, defer-max.
// LDS: 48 + 16 + 9 = 73KB -> 2 blocks/CU.
// ---------------------------------------------------------------------------
__global__ __launch_bounds__(256, 2) void attn_mfma(const u16* __restrict__ qbf,
                                                    const u16* __restrict__ kbuf,
                                                    const u16* __restrict__ vT,
                                                    u16* __restrict__ att,
                                                    float scale) {
    __shared__ __attribute__((aligned(16))) u16 Ks[2][6 * 64 * 32];
    __shared__ __attribute__((aligned(16))) u16 Vs[2 * 128 * 32];
    __shared__ __attribute__((aligned(16))) u16 Ps[4][16 * 72];
    const int j = blockIdx.x;            // 0..15
    const int h = blockIdx.y, b = blockIdx.z;
    const int tid = threadIdx.x, wave = tid >> 6, lane = tid & 63;
    const int l15 = lane & 15, lg = lane >> 4;
    const int lgs = lg ^ ((l15 >> 1) & 3);   // swizzled slot for Ks/Vs reads

    // chunk assignment: g0 -> i=wave, g1 -> i=7-wave  (sum of ktmax equal)
    const int c0 = j + 16 * wave;
    const int c1 = j + 16 * (7 - wave);
    const int ktmax0 = c0 >> 2;          // floor((16*c+15)/64)
    const int ktmax1 = c1 >> 2;
    const int KT = 28 + (j >> 2);        // block-uniform max kt

    const u16* kb_base = kbuf + ((size_t)(h * 2 + b)) * 2048 * 192;
    const u16* vt_base = vT   + ((size_t)(h * 2 + b)) * 128 * 2048;

    const int qmin[2] = {16 * c0, 16 * c1};
    const int qrow[2] = {16 * c0 + l15, 16 * c1 + l15};
    bf16x8 qf[2][6];
#pragma unroll
    for (int g = 0; g < 2; ++g) {
        const size_t qoff = ((size_t)(b * SEQ + qrow[g])) * QROW + h * 192 + lg * 8;
#pragma unroll
        for (int s = 0; s < 6; ++s) qf[g][s] = *(const bf16x8*)&qbf[qoff + s * 32];
    }

    // staging address precompute (loop-invariant; k-loop adds only t0 terms)
    const u16* ksrc[6]; u16* kdstA[6]; u16* kdstB[6];
#pragma unroll
    for (int i = 0; i < 6; ++i) {
        const int base = (wave * 6 + i) * 64;
        const int slot = base + lane;
        const int s = slot >> 8, r = slot & 255, tk = r >> 2, ch = r & 3;
        const int chs = ch ^ ((tk >> 1) & 3);   // inverse swizzle on source
        ksrc[i]  = kb_base + (size_t)tk * 192 + s * 32 + chs * 8;
        kdstA[i] = &Ks[0][base * 8];
        kdstB[i] = &Ks[1][base * 8];
    }
    const u16* vsrc[4]; u16* vdst[4];
#pragma unroll
    for (int i = 0; i < 4; ++i) {
        const int base = (wave * 4 + i) * 64;
        const int slot = base + lane;
        const int s = slot >> 9, r = slot & 511, v = r >> 2, ch = r & 3;
        const int chs = ch ^ ((v >> 1) & 3);
        vsrc[i] = vt_base + (size_t)v * 2048 + s * 32 + chs * 8;
        vdst[i] = &Vs[base * 8];
    }

    floatx4 oacc[2][8];
#pragma unroll
    for (int g = 0; g < 2; ++g)
#pragma unroll
        for (int v = 0; v < 8; ++v) oacc[g][v] = 0.f;
    float m_run[2] = {-1e30f, -1e30f}, l_run[2] = {0.f, 0.f};

    // prologue: K tile 0 -> buf 0 (drained by first vmcnt(10))
#pragma unroll
    for (int i = 0; i < 6; ++i) async_copy16(ksrc[i], kdstA[i]);

    for (int kt = 0; kt <= KT; ++kt) {
        const int t0 = kt * 64;
        const int cur = kt & 1;
        const bool act0 = (kt <= ktmax0), act1 = (kt <= ktmax1);  // act0 => act1

        // issue this tile's V and next tile's K (stay in flight across barriers)
#pragma unroll
        for (int i = 0; i < 4; ++i) async_copy16(vsrc[i] + t0, vdst[i]);
        if (kt < KT) {
            const size_t koff = (size_t)(t0 + 64) * 192;
            u16* const* kd = cur ? kdstA : kdstB;   // next buffer = cur^1
#pragma unroll
            for (int i = 0; i < 6; ++i) async_copy16(ksrc[i] + koff, kd[i]);
            asm volatile("s_waitcnt vmcnt(10)" ::: "memory");  // drain prev K only
        } else {
            asm volatile("s_waitcnt vmcnt(4)" ::: "memory");   // no new K issued
        }
        __builtin_amdgcn_s_barrier();    // Ks[cur] visible to all waves

        // S^T[64t][16q] per active group
        floatx4 sacc[2][4];
#pragma unroll
        for (int g = 0; g < 2; ++g)
#pragma unroll
            for (int mt = 0; mt < 4; ++mt) sacc[g][mt] = 0.f;
        if (act1) {
            __builtin_amdgcn_s_setprio(1);
            if (act0) {
#pragma unroll
                for (int s = 0; s < 6; ++s)
#pragma unroll
                    for (int mt = 0; mt < 4; ++mt) {
                        const bf16x8 kf = *(const bf16x8*)&Ks[cur][(s * 64 + mt * 16 + l15) * 32 + lgs * 8];
                        sacc[0][mt] = __builtin_amdgcn_mfma_f32_16x16x32_bf16(
                            kf, qf[0][s], sacc[0][mt], 0, 0, 0);
                        sacc[1][mt] = __builtin_amdgcn_mfma_f32_16x16x32_bf16(
                            kf, qf[1][s], sacc[1][mt], 0, 0, 0);
                    }
            } else {
#pragma unroll
                for (int s = 0; s < 6; ++s)
#pragma unroll
                    for (int mt = 0; mt < 4; ++mt) {
                        const bf16x8 kf = *(const bf16x8*)&Ks[cur][(s * 64 + mt * 16 + l15) * 32 + lgs * 8];
                        sacc[1][mt] = __builtin_amdgcn_mfma_f32_16x16x32_bf16(
                            kf, qf[1][s], sacc[1][mt], 0, 0, 0);
                    }
            }
            __builtin_amdgcn_s_setprio(0);
        }

        // online softmax per active q-group; pack P to bf16 regs
        u16x4 pk[2][4];
#pragma unroll
        for (int g = 0; g < 2; ++g) {
            if (!(g ? act1 : act0)) continue;
            const bool full = (t0 + 63) <= qmin[g];
            float p[16];
            float tmax = -1e30f;
#pragma unroll
            for (int mt = 0; mt < 4; ++mt)
#pragma unroll
                for (int r = 0; r < 4; ++r) {
                    float v = sacc[g][mt][r] * scale;
                    if (!full) {
                        const int tglob = t0 + mt * 16 + lg * 4 + r;
                        v = (tglob <= qrow[g]) ? v : -1e30f;
                    }
                    p[mt * 4 + r] = v;
                    tmax = fmaxf(tmax, v);
                }
            tmax = fmaxf(tmax, __shfl_xor(tmax, 16));
            tmax = fmaxf(tmax, __shfl_xor(tmax, 32));
            // T13 defer-max: skip O-rescale when tile max grew by <= 8
            const bool defer = __all(tmax <= m_run[g] + 8.0f);
            float alph = 1.0f;
            float mnew = m_run[g];
            if (!defer) {
                mnew = fmaxf(m_run[g], tmax);
                alph = __expf(m_run[g] - mnew);
                m_run[g] = mnew;
            }
            float rsum = 0.f;
#pragma unroll
            for (int k = 0; k < 16; ++k) { p[k] = __expf(p[k] - mnew); rsum += p[k]; }
            rsum += __shfl_xor(rsum, 16);
            rsum += __shfl_xor(rsum, 32);
            if (!defer) {
                l_run[g] = l_run[g] * alph + rsum;
                float af[4];
#pragma unroll
                for (int r = 0; r < 4; ++r) af[r] = __shfl(alph, lg * 4 + r);
#pragma unroll
                for (int vt = 0; vt < 8; ++vt)
#pragma unroll
                    for (int r = 0; r < 4; ++r) oacc[g][vt][r] *= af[r];
            } else {
                l_run[g] += rsum;
            }
#pragma unroll
            for (int mt = 0; mt < 4; ++mt)
#pragma unroll
                for (int r = 0; r < 4; ++r) pk[g][mt][r] = f2bf(p[mt * 4 + r]);
        }

        // Ps round-trip per active g (per-wave buffer, in-wave DS ordering)
        bf16x8 pf[2][2];
#pragma unroll
        for (int g = 0; g < 2; ++g) {
            if (!(g ? act1 : act0)) continue;
#pragma unroll
            for (int mt = 0; mt < 4; ++mt)
                *(u16x4*)&Ps[wave][l15 * 72 + mt * 16 + lg * 4] = pk[g][mt];
#pragma unroll
            for (int s = 0; s < 2; ++s)
                pf[g][s] = *(const bf16x8*)&Ps[wave][l15 * 72 + s * 32 + lg * 8];
        }

        if (kt < KT) asm volatile("s_waitcnt vmcnt(6)" ::: "memory");  // drain V, keep K
        else         asm volatile("s_waitcnt vmcnt(0)" ::: "memory");
        __builtin_amdgcn_s_barrier();    // Vs visible to all waves

        // O += P @ V for active groups; V frag read once feeds both
        if (act1) {
            __builtin_amdgcn_s_setprio(1);
            if (act0) {
#pragma unroll
                for (int s = 0; s < 2; ++s)
#pragma unroll
                    for (int vt = 0; vt < 8; ++vt) {
                        const bf16x8 vf = *(const bf16x8*)&Vs[(s * 128 + vt * 16 + l15) * 32 + lgs * 8];
                        oacc[0][vt] = __builtin_amdgcn_mfma_f32_16x16x32_bf16(
                            pf[0][s], vf, oacc[0][vt], 0, 0, 0);
                        oacc[1][vt] = __builtin_amdgcn_mfma_f32_16x16x32_bf16(
                            pf[1][s], vf, oacc[1][vt], 0, 0, 0);
                    }
            } else {
#pragma unroll
                for (int s = 0; s < 2; ++s)
#pragma unroll
                    for (int vt = 0; vt < 8; ++vt) {
                        const bf16x8 vf = *(const bf16x8*)&Vs[(s * 128 + vt * 16 + l15) * 32 + lgs * 8];
                        oacc[1][vt] = __builtin_amdgcn_mfma_f32_16x16x32_bf16(
                            pf[1][s], vf, oacc[1][vt], 0, 0, 0);
                    }
            }
            __builtin_amdgcn_s_setprio(0);
        }

        // all waves done reading Vs + Ks[cur] before next iter's DMA overwrites
        __builtin_amdgcn_s_barrier();
    }
    // epilogue: divide by l, store bf16 (every chunk has >=1 active tile)
#pragma unroll
    for (int g = 0; g < 2; ++g) {
        float lf[4];
#pragma unroll
        for (int r = 0; r < 4; ++r) lf[r] = 1.0f / __shfl(l_run[g], lg * 4 + r);
#pragma unroll
        for (int vt = 0; vt < 8; ++vt)
#pragma unroll
            for (int r = 0; r < 4; ++r) {
                const int orow = b * SEQ + qmin[g] + lg * 4 + r;
                att[(size_t)orow * 2048 + h * 128 + vt * 16 + l15] =
                    f2bf(oacc[g][vt][r] * lf[r]);
            }
    }
}

// ---------------------------------------------------------------------------
extern "C" void kernel_launch(void* const* d_in, const int* in_sizes, int n_in,
                              void* d_out, int out_size, void* d_ws, size_t ws_size,
                              hipStream_t stream) {
    const float* x     = (const float*)d_in[0];
    const float* wq    = (const float*)d_in[1];
    const float* wkv_a = (const float*)d_in[2];
    const float* knw   = (const float*)d_in[3];
    const float* wkv_b = (const float*)d_in[4];
    const float* wo    = (const float*)d_in[5];
    const float* fcos  = (const float*)d_in[6];
    const float* fsin  = (const float*)d_in[7];
    float* out = (float*)d_out;

    char* w = (char*)d_ws;
    u16*   x_bf    = (u16*)w;  w += (size_t)NTOK * 2048 * 2;
    u16*   wq_bf   = (u16*)w;  w += (size_t)QROW * 2048 * 2;
    u16*   wkva_bf = (u16*)w;  w += (size_t)640 * 2048 * 2;
    u16*   wkvb_bf = (u16*)w;  w += (size_t)KVBROW * KV_LORA * 2;
    u16*   wo_bf   = (u16*)w;  w += (size_t)2048 * 2048 * 2;
    u16*   q_bf    = (u16*)w;  w += (size_t)NTOK * QROW * 2;
    float* kv_raw  = (float*)w; w += (size_t)NTOK * 640 * 4;
    u16*   kvn_bf  = (u16*)w;  w += (size_t)NTOK * KV_LORA * 2;
    u16*   kbuf    = (u16*)w;  w += (size_t)NH * NB * SEQ * 192 * 2;
    u16*   vT      = (u16*)w;  w += (size_t)NH * NB * 128 * SEQ * 2;
    u16*   att_bf  = (u16*)w;  w += (size_t)NTOK * 2048 * 2;

    const double mm = 0.1 * 1.0 * log(40.0) + 1.0;
    const float scale = (float)((1.0 / sqrt((double)D_QK)) * mm * mm);

    dim3 blk(256);
    cast_all<<<dim3(21760), blk, 0, stream>>>(x, wq, wkv_a, wkv_b, wo,
                                              x_bf, wq_bf, wkva_bf, wkvb_bf, wo_bf);
    gemm_mfma<1><<<dim3(QROW / 128, NTOK / 128), blk, 0, stream>>>(
        x_bf, wq_bf, q_bf, nullptr, nullptr, NTOK, QROW, 2048);
    gemm_mfma<0><<<dim3(640 / 128, NTOK / 128), blk, 0, stream>>>(
        x_bf, wkva_bf, kv_raw, nullptr, nullptr, NTOK, 640, 2048);
    kv_fix<<<dim3(NTOK), blk, 0, stream>>>(kv_raw, knw, fcos, fsin, kvn_bf, kbuf);
    gemm_mfma<2><<<dim3(KVBROW / 128, NTOK / 128), blk, 0, stream>>>(
        kvn_bf, wkvb_bf, nullptr, kbuf, vT, NTOK, KVBROW, KV_LORA);
    attn_mfma<<<dim3(16, NH, NB), blk, 0, stream>>>(q_bf, kbuf, vT, att_bf, scale);
    gemm_mfma<0><<<dim3(2048 / 128, NTOK / 128), blk, 0, stream>>>(
        att_bf, wo_bf, out, nullptr, nullptr, NTOK, 2048, 2048);
}

// Round 6
// 468.050 us; speedup vs baseline: 1.0441x; 1.0441x over previous
//
#include <hip/hip_runtime.h>
#include <math.h>

#define NH      16
#define D_NOPE  128
#define D_ROPE  64
#define D_QK    192
#define D_V     128
#define KV_LORA 512
#define NB      2
#define SEQ     2048
#define NTOK    (NB*SEQ)          // 4096
#define QROW    (NH*D_QK)         // 3072
#define KVBROW  (NH*(D_NOPE+D_V)) // 4096
#define EPSF    1e-6f

typedef unsigned short u16;
typedef float  floatx4 __attribute__((ext_vector_type(4)));
typedef __bf16 bf16x8  __attribute__((ext_vector_type(8)));
typedef u16    u16x4   __attribute__((ext_vector_type(4)));
typedef u16    u16x8   __attribute__((ext_vector_type(8)));

__device__ __forceinline__ u16 f2bf(float f) {
    unsigned u = __builtin_bit_cast(unsigned, f);
    return (u16)((u + 0x7fffu + ((u >> 16) & 1u)) >> 16);
}

__device__ __forceinline__ void async_copy16(const void* g, void* l) {
    __builtin_amdgcn_global_load_lds(
        (const __attribute__((address_space(1))) unsigned int*)g,
        (__attribute__((address_space(3))) unsigned int*)l,
        16, 0, 0);
}

// ---------------------------------------------------------------------------
// Fused fp32->bf16 cast of all 5 weight/activation arrays in ONE dispatch.
// ---------------------------------------------------------------------------
__global__ __launch_bounds__(256) void cast_all(const float* __restrict__ x,
                                                const float* __restrict__ wq,
                                                const float* __restrict__ wkva,
                                                const float* __restrict__ wkvb,
                                                const float* __restrict__ wo,
                                                u16* __restrict__ xb,
                                                u16* __restrict__ wqb,
                                                u16* __restrict__ wkvab,
                                                u16* __restrict__ wkvbb,
                                                u16* __restrict__ wob) {
    int blk = blockIdx.x;
    const float* src; u16* dst; bool pad = false;
    if (blk < 8192)        { src = x;    dst = xb; }
    else if (blk < 14336)  { blk -= 8192;  src = wq;   dst = wqb; }
    else if (blk < 15616)  { blk -= 14336; src = wkva; dst = wkvab; pad = true; }
    else if (blk < 17664)  { blk -= 15616; src = wkvb; dst = wkvbb; }
    else                   { blk -= 17664; src = wo;   dst = wob; }
    const int i = (blk * 256 + threadIdx.x) * 4;
    u16x4 o;
    if (pad && (i >> 11) >= 576) {
        o[0] = 0; o[1] = 0; o[2] = 0; o[3] = 0;
    } else {
        const float4 v = *(const float4*)&src[i];
        o[0] = f2bf(v.x); o[1] = f2bf(v.y); o[2] = f2bf(v.z); o[3] = f2bf(v.w);
    }
    *(u16x4*)&dst[i] = o;
}

// ---------------------------------------------------------------------------
// bf16 NT MFMA GEMM (m97 recipe), templated epilogue:
//   MODE 0: fp32 C[M,N] | MODE 1: bf16 C[M,N] | MODE 2: kv-split kbuf/vT.
// ---------------------------------------------------------------------------
template<int MODE>
__global__ __launch_bounds__(256) void gemm_mfma(const u16* __restrict__ A,
                                                 const u16* __restrict__ B,
                                                 void* __restrict__ Cout,
                                                 u16* __restrict__ kbuf,
                                                 u16* __restrict__ vT,
                                                 int M, int N, int K) {
    __shared__ u16 As[128 * 32];
    __shared__ u16 Bs[128 * 32];
    const int tid  = threadIdx.x;
    const int wave = tid >> 6, lane = tid & 63;
    const int m0 = blockIdx.y * 128, n0 = blockIdx.x * 128;
    const int wm = (wave & 1) * 64, wn = (wave >> 1) * 64;

    const int srow = wave * 32 + (lane >> 2);
    const int kch  = (lane & 3) * 8;
    const u16* gA0 = A + (size_t)(m0 + srow) * K + kch;
    const u16* gA1 = gA0 + (size_t)16 * K;
    const u16* gB0 = B + (size_t)(n0 + srow) * K + kch;
    const u16* gB1 = gB0 + (size_t)16 * K;
    u16* lA0 = &As[(wave * 32) * 32];
    u16* lA1 = &As[(wave * 32 + 16) * 32];
    u16* lB0 = &Bs[(wave * 32) * 32];
    u16* lB1 = &Bs[(wave * 32 + 16) * 32];

    floatx4 acc[4][4];
#pragma unroll
    for (int i = 0; i < 4; ++i)
#pragma unroll
        for (int j = 0; j < 4; ++j) acc[i][j] = 0.f;

    const int lrow = lane & 15;
    const int lkh  = (lane >> 4) * 8;

    for (int k0 = 0; k0 < K; k0 += 32) {
        __syncthreads();
        async_copy16(gA0 + k0, lA0);
        async_copy16(gA1 + k0, lA1);
        async_copy16(gB0 + k0, lB0);
        async_copy16(gB1 + k0, lB1);
        __syncthreads();
        bf16x8 a[4], b[4];
#pragma unroll
        for (int mi = 0; mi < 4; ++mi)
            a[mi] = *(const bf16x8*)&As[(wm + mi * 16 + lrow) * 32 + lkh];
#pragma unroll
        for (int ni = 0; ni < 4; ++ni)
            b[ni] = *(const bf16x8*)&Bs[(wn + ni * 16 + lrow) * 32 + lkh];
#pragma unroll
        for (int mi = 0; mi < 4; ++mi)
#pragma unroll
            for (int ni = 0; ni < 4; ++ni)
                acc[mi][ni] = __builtin_amdgcn_mfma_f32_16x16x32_bf16(
                    a[mi], b[ni], acc[mi][ni], 0, 0, 0);
    }

    const int crow = (lane >> 4) * 4, ccol = lane & 15;
#pragma unroll
    for (int mi = 0; mi < 4; ++mi)
#pragma unroll
        for (int ni = 0; ni < 4; ++ni) {
            const int m = m0 + wm + mi * 16 + crow;
            const int c = n0 + wn + ni * 16 + ccol;
            if (MODE == 0) {
                float* cp = (float*)Cout + (size_t)m * N + c;
#pragma unroll
                for (int r = 0; r < 4; ++r) cp[(size_t)r * N] = acc[mi][ni][r];
            } else if (MODE == 1) {
                u16* cp = (u16*)Cout + (size_t)m * N + c;
#pragma unroll
                for (int r = 0; r < 4; ++r) cp[(size_t)r * N] = f2bf(acc[mi][ni][r]);
            } else {
                const int hh = c >> 8, j = c & 255;
                const int bb = m >> 11, t = m & 2047;
                if (j < 128) {
#pragma unroll
                    for (int r = 0; r < 4; ++r)
                        kbuf[(((size_t)hh * 2 + bb) * 2048 + t + r) * 192 + j] =
                            f2bf(acc[mi][ni][r]);
                } else {
                    u16x4 pk;
#pragma unroll
                    for (int r = 0; r < 4; ++r) pk[r] = f2bf(acc[mi][ni][r]);
                    *(u16x4*)&vT[(((size_t)hh * 2 + bb) * 128 + (j - 128)) * 2048 + t] = pk;
                }
            }
        }
}

// NOTE: the reference computes q_pe = rotary(q_pe) but then uses the ORIGINAL
// (unrotated) q in the score einsum — the rotated q_pe is dead code there.
// So q gets NO RoPE; only k_pe is rotated.

// ---------------------------------------------------------------------------
// Per-token: rmsnorm(kv_c)*w -> kvn_bf; rotary(k_pe) -> kbuf[h][b][t][128..191].
// ---------------------------------------------------------------------------
__global__ __launch_bounds__(256) void kv_fix(const float* __restrict__ kv_raw,
                                              const float* __restrict__ w,
                                              const float* __restrict__ fcos,
                                              const float* __restrict__ fsin,
                                              u16* __restrict__ kvn_bf,
                                              u16* __restrict__ kbuf) {
    const int row = blockIdx.x;
    const int tid = threadIdx.x;
    const float* src = kv_raw + (size_t)row * 640;
    const float v0 = src[tid];
    const float v1 = src[256 + tid];
    float ss = v0 * v0 + v1 * v1;
#pragma unroll
    for (int off = 32; off > 0; off >>= 1) ss += __shfl_down(ss, off, 64);
    __shared__ float red[4];
    __shared__ float kpe_s[64];
    if ((tid & 63) == 0) red[tid >> 6] = ss;
    if (tid < 32) {
        const int s = row & (SEQ - 1);
        const float c  = fcos[s * 32 + tid];
        const float sn = fsin[s * 32 + tid];
        const float xr = src[KV_LORA + 2 * tid];
        const float xi = src[KV_LORA + 2 * tid + 1];
        kpe_s[2 * tid]     = xr * c - xi * sn;
        kpe_s[2 * tid + 1] = xr * sn + xi * c;
    }
    __syncthreads();
    const float tot = red[0] + red[1] + red[2] + red[3];
    const float inv = rsqrtf(tot * (1.0f / KV_LORA) + EPSF);
    kvn_bf[(size_t)row * KV_LORA + tid]       = f2bf(v0 * inv * w[tid]);
    kvn_bf[(size_t)row * KV_LORA + 256 + tid] = f2bf(v1 * inv * w[256 + tid]);
    const int bb = row >> 11, t = row & 2047;
    const int hh = tid >> 4, dg = (tid & 15) * 4;
    u16x4 pk;
#pragma unroll
    for (int j = 0; j < 4; ++j) pk[j] = f2bf(kpe_s[dg + j]);
    *(u16x4*)&kbuf[(((size_t)hh * 2 + bb) * 2048 + t) * 192 + 128 + dg] = pk;
}

// ---------------------------------------------------------------------------
// MFMA flash attention v9: pair-concurrent 8-wave blocks.
//   One block per qt-PAIR (qa, qb=15-qa): 256 blocks x 512 threads. Wave w:
//   g0 = rows [qa*128+w*16, +16), g1 = rows [qb*128+w*16, +16). The staged
//   K/V tile serves BOTH q-tiles while qa is live (kf/vf shared, v7-style);
//   qa's tiles are a prefix of qb's -> trip count 32-2qa, total iters/hb
//   = 200 vs v7's 272 (0.74x staging). 8 waves = 2/SIMD held constant
//   (1 block/CU), vs v7's collapse to 1 wave/SIMD (measured 13.2% occ).
//   K AND V double-buffered -> ONE barrier/iter; stage(kt+1) issued right
//   after the barrier -> full-iteration load slack before next vmcnt(0).
//   No runtime-indexed arrays (flat LDS + computed offsets; v8's spill fix).
//   XCD swizzle: grid (32 hb, 8 qa) so same-(h,b) blocks share one XCD L2.
//   Keeps: T2 both-sides XOR swizzle, setprio, defer-max.
// LDS: Ks 2x24KB + Vs 2x16KB + Ps 18KB = 98KB -> 1 block/CU.
// ---------------------------------------------------------------------------
#define KS_HALF (6 * 64 * 32)     // 12288 u16
#define VS_HALF (2 * 128 * 32)    // 8192 u16
__global__ __launch_bounds__(512, 2) void attn_mfma(const u16* __restrict__ qbf,
                                                    const u16* __restrict__ kbuf,
                                                    const u16* __restrict__ vT,
                                                    u16* __restrict__ att,
                                                    float scale) {
    __shared__ __attribute__((aligned(16))) u16 KsF[2 * KS_HALF];
    __shared__ __attribute__((aligned(16))) u16 VsF[2 * VS_HALF];
    __shared__ __attribute__((aligned(16))) u16 Ps[8][16 * 72];
    const int hb = blockIdx.x;           // 0..31  (same hb -> same XCD)
    const int qa = blockIdx.y;           // 0..7
    const int qb = 15 - qa;
    const int h = hb >> 1, b = hb & 1;
    const int tid = threadIdx.x, wave = tid >> 6, lane = tid & 63;
    const int l15 = lane & 15, lg = lane >> 4;
    const int lgs = lg ^ ((l15 >> 1) & 3);   // swizzled slot for Ks/Vs reads

    const u16* kb_base = kbuf + ((size_t)(h * 2 + b)) * 2048 * 192;
    const u16* vt_base = vT   + ((size_t)(h * 2 + b)) * 128 * 2048;

    const int qbase0 = qa * 128 + wave * 16;
    const int qbase1 = qb * 128 + wave * 16;
    bf16x8 qf[2][6];
    {
        const size_t q0 = ((size_t)(b * SEQ + qbase0 + l15)) * QROW + h * 192 + lg * 8;
        const size_t q1 = ((size_t)(b * SEQ + qbase1 + l15)) * QROW + h * 192 + lg * 8;
#pragma unroll
        for (int s = 0; s < 6; ++s) {
            qf[0][s] = *(const bf16x8*)&qbf[q0 + s * 32];
            qf[1][s] = *(const bf16x8*)&qbf[q1 + s * 32];
        }
    }

    // staging precompute: K 3 loads/wave, V 2 loads/wave (flat offsets)
    const u16* ksrc0; const u16* ksrc1; const u16* ksrc2;
    int kbo0, kbo1, kbo2;
    {
        const int b0 = (wave * 3 + 0) * 64, s0 = (b0 + lane) >> 8, r0 = (b0 + lane) & 255;
        const int b1 = (wave * 3 + 1) * 64, s1 = (b1 + lane) >> 8, r1 = (b1 + lane) & 255;
        const int b2 = (wave * 3 + 2) * 64, s2 = (b2 + lane) >> 8, r2 = (b2 + lane) & 255;
        const int tk0 = r0 >> 2, tk1 = r1 >> 2, tk2 = r2 >> 2;
        ksrc0 = kb_base + (size_t)tk0 * 192 + s0 * 32 + ((r0 & 3) ^ ((tk0 >> 1) & 3)) * 8;
        ksrc1 = kb_base + (size_t)tk1 * 192 + s1 * 32 + ((r1 & 3) ^ ((tk1 >> 1) & 3)) * 8;
        ksrc2 = kb_base + (size_t)tk2 * 192 + s2 * 32 + ((r2 & 3) ^ ((tk2 >> 1) & 3)) * 8;
        kbo0 = b0 * 8; kbo1 = b1 * 8; kbo2 = b2 * 8;
    }
    const u16* vsrc0; const u16* vsrc1;
    int vbo0, vbo1;
    {
        const int b0 = (wave * 2 + 0) * 64, s0 = (b0 + lane) >> 9, r0 = (b0 + lane) & 511;
        const int b1 = (wave * 2 + 1) * 64, s1 = (b1 + lane) >> 9, r1 = (b1 + lane) & 511;
        const int v0 = r0 >> 2, v1 = r1 >> 2;
        vsrc0 = vt_base + (size_t)v0 * 2048 + s0 * 32 + ((r0 & 3) ^ ((v0 >> 1) & 3)) * 8;
        vsrc1 = vt_base + (size_t)v1 * 2048 + s1 * 32 + ((v1 >> 1 & 3) != 0 ? ((r1 & 3) ^ ((v1 >> 1) & 3)) : (r1 & 3)) * 8;
        // (identical formula; written plainly below for clarity)
        vsrc1 = vt_base + (size_t)v1 * 2048 + s1 * 32 + ((r1 & 3) ^ ((v1 >> 1) & 3)) * 8;
        vbo0 = b0 * 8; vbo1 = b1 * 8;
    }

    floatx4 oacc[2][8];
#pragma unroll
    for (int g = 0; g < 2; ++g)
#pragma unroll
        for (int v = 0; v < 8; ++v) oacc[g][v] = 0.f;
    float m_run[2] = {-1e30f, -1e30f}, l_run[2] = {0.f, 0.f};

    const int nt = 32 - 2 * qa;          // block trip count
    const int ktmax0 = 2 * qa + 1;       // last active tile for g0

    // prologue: stage tile 0 into half 0
    async_copy16(ksrc0, &KsF[kbo0]);
    async_copy16(ksrc1, &KsF[kbo1]);
    async_copy16(ksrc2, &KsF[kbo2]);
    async_copy16(vsrc0, &VsF[vbo0]);
    async_copy16(vsrc1, &VsF[vbo1]);

    for (int kt = 0; kt < nt; ++kt) {
        const int t0 = kt * 64;
        const int cur = kt & 1;
        const int kco = cur * KS_HALF;   // current K half offset
        const int vco = cur * VS_HALF;
        const bool act0 = (kt <= ktmax0);

        asm volatile("s_waitcnt vmcnt(0)" ::: "memory");   // tile kt landed (1-iter slack)
        __builtin_amdgcn_s_barrier();

        // stage tile kt+1 into the other half (full iteration to land)
        if (kt + 1 < nt) {
            const int kno = (cur ^ 1) * KS_HALF;
            const int vno = (cur ^ 1) * VS_HALF;
            const size_t ko = (size_t)(t0 + 64) * 192;
            async_copy16(ksrc0 + ko, &KsF[kno + kbo0]);
            async_copy16(ksrc1 + ko, &KsF[kno + kbo1]);
            async_copy16(ksrc2 + ko, &KsF[kno + kbo2]);
            async_copy16(vsrc0 + t0 + 64, &VsF[vno + vbo0]);
            async_copy16(vsrc1 + t0 + 64, &VsF[vno + vbo1]);
        }

        // QK: S^T[64t][16q] per group; kf shared across both groups
        floatx4 sacc0[4], sacc1[4];
#pragma unroll
        for (int mt = 0; mt < 4; ++mt) { sacc0[mt] = 0.f; sacc1[mt] = 0.f; }
        __builtin_amdgcn_s_setprio(1);
        if (act0) {
#pragma unroll
            for (int s = 0; s < 6; ++s)
#pragma unroll
                for (int mt = 0; mt < 4; ++mt) {
                    const bf16x8 kf = *(const bf16x8*)&KsF[kco + (s * 64 + mt * 16 + l15) * 32 + lgs * 8];
                    sacc0[mt] = __builtin_amdgcn_mfma_f32_16x16x32_bf16(
                        kf, qf[0][s], sacc0[mt], 0, 0, 0);
                    sacc1[mt] = __builtin_amdgcn_mfma_f32_16x16x32_bf16(
                        kf, qf[1][s], sacc1[mt], 0, 0, 0);
                }
        } else {
#pragma unroll
            for (int s = 0; s < 6; ++s)
#pragma unroll
                for (int mt = 0; mt < 4; ++mt) {
                    const bf16x8 kf = *(const bf16x8*)&KsF[kco + (s * 64 + mt * 16 + l15) * 32 + lgs * 8];
                    sacc1[mt] = __builtin_amdgcn_mfma_f32_16x16x32_bf16(
                        kf, qf[1][s], sacc1[mt], 0, 0, 0);
                }
        }
        __builtin_amdgcn_s_setprio(0);

        // online softmax per active group; pack P; Ps round-trip -> pf
        bf16x8 pf[2][2];
#pragma unroll
        for (int g = 0; g < 2; ++g) {
            if (g == 0 && !act0) continue;
            floatx4* sc = g ? sacc1 : sacc0;
            const int qbase = g ? qbase1 : qbase0;
            const bool full = (t0 + 63) <= qbase;
            float p[16];
            float tmax = -1e30f;
#pragma unroll
            for (int mt = 0; mt < 4; ++mt)
#pragma unroll
                for (int r = 0; r < 4; ++r) {
                    float v = sc[mt][r] * scale;
                    if (!full) {
                        const int tglob = t0 + mt * 16 + lg * 4 + r;
                        v = (tglob <= qbase + l15) ? v : -1e30f;
                    }
                    p[mt * 4 + r] = v;
                    tmax = fmaxf(tmax, v);
                }
            tmax = fmaxf(tmax, __shfl_xor(tmax, 16));
            tmax = fmaxf(tmax, __shfl_xor(tmax, 32));
            // T13 defer-max: skip O-rescale when tile max grew by <= 8
            const bool defer = __all(tmax <= m_run[g] + 8.0f);
            float mnew = m_run[g];
            if (!defer) {
                mnew = fmaxf(m_run[g], tmax);
                const float alph = __expf(m_run[g] - mnew);
                m_run[g] = mnew;
                float af[4];
#pragma unroll
                for (int r = 0; r < 4; ++r) af[r] = __shfl(alph, lg * 4 + r);
#pragma unroll
                for (int vt = 0; vt < 8; ++vt)
#pragma unroll
                    for (int r = 0; r < 4; ++r) oacc[g][vt][r] *= af[r];
                l_run[g] *= alph;
            }
            float rsum = 0.f;
#pragma unroll
            for (int k = 0; k < 16; ++k) { p[k] = __expf(p[k] - mnew); rsum += p[k]; }
            rsum += __shfl_xor(rsum, 16);
            rsum += __shfl_xor(rsum, 32);
            l_run[g] += rsum;
#pragma unroll
            for (int mt = 0; mt < 4; ++mt) {
                u16x4 pk;
#pragma unroll
                for (int r = 0; r < 4; ++r) pk[r] = f2bf(p[mt * 4 + r]);
                *(u16x4*)&Ps[wave][l15 * 72 + mt * 16 + lg * 4] = pk;
            }
#pragma unroll
            for (int s = 0; s < 2; ++s)
                pf[g][s] = *(const bf16x8*)&Ps[wave][l15 * 72 + s * 32 + lg * 8];
        }

        // PV: O += P @ V ; vf shared across both groups
        __builtin_amdgcn_s_setprio(1);
        if (act0) {
#pragma unroll
            for (int s = 0; s < 2; ++s)
#pragma unroll
                for (int vt = 0; vt < 8; ++vt) {
                    const bf16x8 vf = *(const bf16x8*)&VsF[vco + (s * 128 + vt * 16 + l15) * 32 + lgs * 8];
                    oacc[0][vt] = __builtin_amdgcn_mfma_f32_16x16x32_bf16(
                        pf[0][s], vf, oacc[0][vt], 0, 0, 0);
                    oacc[1][vt] = __builtin_amdgcn_mfma_f32_16x16x32_bf16(
                        pf[1][s], vf, oacc[1][vt], 0, 0, 0);
                }
        } else {
#pragma unroll
            for (int s = 0; s < 2; ++s)
#pragma unroll
                for (int vt = 0; vt < 8; ++vt) {
                    const bf16x8 vf = *(const bf16x8*)&VsF[vco + (s * 128 + vt * 16 + l15) * 32 + lgs * 8];
                    oacc[1][vt] = __builtin_amdgcn_mfma_f32_16x16x32_bf16(
                        pf[1][s], vf, oacc[1][vt], 0, 0, 0);
                }
        }
        __builtin_amdgcn_s_setprio(0);
        // no trailing barrier: next iter's top barrier protects buffer reuse
        // (staging writes half [cur^1], whose readers passed this iter's barrier)
    }

    // epilogue: divide by l, store bf16 for both groups
#pragma unroll
    for (int g = 0; g < 2; ++g) {
        const int qbase = g ? qbase1 : qbase0;
        float lf[4];
#pragma unroll
        for (int r = 0; r < 4; ++r) lf[r] = 1.0f / __shfl(l_run[g], lg * 4 + r);
#pragma unroll
        for (int vt = 0; vt < 8; ++vt)
#pragma unroll
            for (int r = 0; r < 4; ++r) {
                const int orow = b * SEQ + qbase + lg * 4 + r;
                att[(size_t)orow * 2048 + h * 128 + vt * 16 + l15] =
                    f2bf(oacc[g][vt][r] * lf[r]);
            }
    }
}

// ---------------------------------------------------------------------------
extern "C" void kernel_launch(void* const* d_in, const int* in_sizes, int n_in,
                              void* d_out, int out_size, void* d_ws, size_t ws_size,
                              hipStream_t stream) {
    const float* x     = (const float*)d_in[0];
    const float* wq    = (const float*)d_in[1];
    const float* wkv_a = (const float*)d_in[2];
    const float* knw   = (const float*)d_in[3];
    const float* wkv_b = (const float*)d_in[4];
    const float* wo    = (const float*)d_in[5];
    const float* fcos  = (const float*)d_in[6];
    const float* fsin  = (const float*)d_in[7];
    float* out = (float*)d_out;

    char* w = (char*)d_ws;
    u16*   x_bf    = (u16*)w;  w += (size_t)NTOK * 2048 * 2;
    u16*   wq_bf   = (u16*)w;  w += (size_t)QROW * 2048 * 2;
    u16*   wkva_bf = (u16*)w;  w += (size_t)640 * 2048 * 2;
    u16*   wkvb_bf = (u16*)w;  w += (size_t)KVBROW * KV_LORA * 2;
    u16*   wo_bf   = (u16*)w;  w += (size_t)2048 * 2048 * 2;
    u16*   q_bf    = (u16*)w;  w += (size_t)NTOK * QROW * 2;
    float* kv_raw  = (float*)w; w += (size_t)NTOK * 640 * 4;
    u16*   kvn_bf  = (u16*)w;  w += (size_t)NTOK * KV_LORA * 2;
    u16*   kbuf    = (u16*)w;  w += (size_t)NH * NB * SEQ * 192 * 2;
    u16*   vT      = (u16*)w;  w += (size_t)NH * NB * 128 * SEQ * 2;
    u16*   att_bf  = (u16*)w;  w += (size_t)NTOK * 2048 * 2;

    const double mm = 0.1 * 1.0 * log(40.0) + 1.0;
    const float scale = (float)((1.0 / sqrt((double)D_QK)) * mm * mm);

    dim3 blk(256);
    cast_all<<<dim3(21760), blk, 0, stream>>>(x, wq, wkv_a, wkv_b, wo,
                                              x_bf, wq_bf, wkva_bf, wkvb_bf, wo_bf);
    gemm_mfma<1><<<dim3(QROW / 128, NTOK / 128), blk, 0, stream>>>(
        x_bf, wq_bf, q_bf, nullptr, nullptr, NTOK, QROW, 2048);
    gemm_mfma<0><<<dim3(640 / 128, NTOK / 128), blk, 0, stream>>>(
        x_bf, wkva_bf, kv_raw, nullptr, nullptr, NTOK, 640, 2048);
    kv_fix<<<dim3(NTOK), blk, 0, stream>>>(kv_raw, knw, fcos, fsin, kvn_bf, kbuf);
    gemm_mfma<2><<<dim3(KVBROW / 128, NTOK / 128), blk, 0, stream>>>(
        kvn_bf, wkvb_bf, nullptr, kbuf, vT, NTOK, KVBROW, KV_LORA);
    attn_mfma<<<dim3(32, 8, 1), dim3(512), 0, stream>>>(q_bf, kbuf, vT, att_bf, scale);
    gemm_mfma<0><<<dim3(2048 / 128, NTOK / 128), blk, 0, stream>>>(
        att_bf, wo_bf, out, nullptr, nullptr, NTOK, 2048, 2048);
}